// Round 3
// baseline (523.672 us; speedup 1.0000x reference)
//
#include <hip/hip_runtime.h>

#define NTOK 4096
#define CH 64
#define LOG2E 1.4426950408889634f

typedef __bf16 bf8 __attribute__((ext_vector_type(8)));
typedef __bf16 bf4 __attribute__((ext_vector_type(4)));
typedef _Float16 h8 __attribute__((ext_vector_type(8)));
typedef _Float16 h4 __attribute__((ext_vector_type(4)));
typedef __fp16 fp16x2 __attribute__((ext_vector_type(2)));
typedef float f4 __attribute__((ext_vector_type(4)));

__device__ __forceinline__ f4 mfma16(bf8 a, bf8 b, f4 c) {
    return __builtin_amdgcn_mfma_f32_16x16x32_bf16(a, b, c, 0, 0, 0);
}
__device__ __forceinline__ f4 mfma32h(h8 a, h8 b, f4 c) {
    return __builtin_amdgcn_mfma_f32_16x16x32_f16(a, b, c, 0, 0, 0);
}

// ---------------- fused pre-pass: blocks 0..3 = weight transpose; 4..515 = GN partials ----
__global__ __launch_bounds__(256) void pre_kernel(const float* __restrict__ wq,
                                                  const float* __restrict__ wk,
                                                  const float* __restrict__ wv,
                                                  const float* __restrict__ wp,
                                                  const float* __restrict__ x,
                                                  __bf16* __restrict__ wqt,
                                                  __bf16* __restrict__ wkt,
                                                  __bf16* __restrict__ wvt,
                                                  __bf16* __restrict__ wpt,
                                                  float* __restrict__ gpart) {
    int t = threadIdx.x;
    if (blockIdx.x < 4) {   // weight transpose + bf16 convert
        int m = blockIdx.x;
        const float* src = (m == 0) ? wq : (m == 1) ? wk : (m == 2) ? wv : wp;
        __bf16* dst      = (m == 0) ? wqt : (m == 1) ? wkt : (m == 2) ? wvt : wpt;
        __shared__ float s[64][65];
        for (int i = 0; i < 16; ++i) {
            int e = i * 256 + t;
            s[e >> 6][e & 63] = src[e];
        }
        __syncthreads();
        int o = t >> 2, seg = t & 3;
        for (int j = 0; j < 16; ++j) {
            int in = seg * 16 + j;
            dst[o * 64 + in] = (__bf16)s[in][o];
        }
        return;
    }
    // GN partial sums: 512 blocks = 8b x 64 slabs of 64 rows
    int bid = blockIdx.x - 4;
    int b = bid >> 6, slab = bid & 63;
    const float4* xb = (const float4*)(x + (size_t)(b * NTOK + slab * 64) * CH);
    float s = 0.f, ss = 0.f;
    for (int i = 0; i < 4; ++i) {
        int row = (t >> 4) + i * 16;
        float4 v = xb[row * 16 + (t & 15)];
        s  += v.x + v.y + v.z + v.w;
        ss += v.x * v.x + v.y * v.y + v.z * v.z + v.w * v.w;
    }
    __shared__ float ls[256], lss[256];
    ls[t] = s; lss[t] = ss;
    __syncthreads();
    if (t < 8) {
        float a = 0.f, aa = 0.f;
        for (int p = 0; p < 16; ++p) {
            a  += ls[p * 16 + 2 * t]  + ls[p * 16 + 2 * t + 1];
            aa += lss[p * 16 + 2 * t] + lss[p * 16 + 2 * t + 1];
        }
        gpart[((b * 64 + slab) * 8 + t) * 2 + 0] = a;
        gpart[((b * 64 + slab) * 8 + t) * 2 + 1] = aa;
    }
}

// ---------------- fused GN + QKV projection (grid 512, 64 rows/block) --------------------
// V written fp16 in slot-permuted K=32 fragment layout:
//   vt[((b*128 + kt32)*4 + td)*64 + lane] (h8): lane=(quad,l15) holds
//   V^T[d=td*16+l15][slot quad*8+j], slot j<4 -> key quad*4+j ; j>=4 -> 16+quad*4+(j-4)
__global__ __launch_bounds__(256) void qkv_gn(const float* __restrict__ x,
                                              const float* __restrict__ gpart,
                                              const float* __restrict__ gamma,
                                              const float* __restrict__ beta,
                                              const __bf16* __restrict__ wqt,
                                              const __bf16* __restrict__ wkt,
                                              const __bf16* __restrict__ wvt,
                                              const float* __restrict__ bq,
                                              const float* __restrict__ bk,
                                              const float* __restrict__ bv,
                                              __bf16* __restrict__ q,
                                              __bf16* __restrict__ k,
                                              _Float16* __restrict__ vT) {
    __shared__ __bf16 W[3][64][72];
    __shared__ __bf16 Hl[64][72];
    __shared__ _Float16 Vst[64][68];
    __shared__ float red[128];
    __shared__ float sstat[16];
    int t = threadIdx.x;
    size_t rowbase = (size_t)blockIdx.x * 64;
    int b = (int)(rowbase >> 12), tokbase = (int)(rowbase & 4095);
    if (t < 64) {
        int gi = t & 7, c = t >> 3;
        const float2* gp = (const float2*)gpart + (size_t)b * 512 + gi;
        float a = 0.f, aa = 0.f;
        for (int p = c * 8; p < c * 8 + 8; ++p) {
            float2 v = gp[(size_t)p * 8];
            a += v.x; aa += v.y;
        }
        red[t * 2] = a; red[t * 2 + 1] = aa;
    }
    for (int m = 0; m < 3; ++m) {
        const __bf16* src = (m == 0) ? wqt : (m == 1) ? wkt : wvt;
        for (int i = 0; i < 2; ++i) {
            int e = i * 256 + t, row = e >> 3, ch = e & 7;
            *(bf8*)&W[m][row][ch * 8] = *(const bf8*)(src + row * 64 + ch * 8);
        }
    }
    __syncthreads();
    if (t < 8) {
        float a = 0.f, aa = 0.f;
        for (int c = 0; c < 8; ++c) {
            a  += red[(c * 8 + t) * 2];
            aa += red[(c * 8 + t) * 2 + 1];
        }
        float mean = a * (1.f / 32768.f);
        float var = aa * (1.f / 32768.f) - mean * mean;
        sstat[t * 2 + 0] = mean;
        sstat[t * 2 + 1] = rsqrtf(var + 1e-3f);
    }
    __syncthreads();
    {
        int c4 = (t & 15) * 4, grp = c4 >> 3;
        float mean = sstat[grp * 2], rstd = sstat[grp * 2 + 1];
        float g0 = gamma[c4] * rstd, g1 = gamma[c4 + 1] * rstd,
              g2 = gamma[c4 + 2] * rstd, g3 = gamma[c4 + 3] * rstd;
        float b0 = beta[c4], b1 = beta[c4 + 1], b2 = beta[c4 + 2], b3 = beta[c4 + 3];
        const float4* xb = (const float4*)(x + rowbase * 64);
        for (int i = 0; i < 4; ++i) {
            int row = (t >> 4) + i * 16;
            float4 v = xb[row * 16 + (t & 15)];
            bf4 hv;
            hv[0] = (__bf16)((v.x - mean) * g0 + b0);
            hv[1] = (__bf16)((v.y - mean) * g1 + b1);
            hv[2] = (__bf16)((v.z - mean) * g2 + b2);
            hv[3] = (__bf16)((v.w - mean) * g3 + b3);
            *(bf4*)&Hl[row][c4] = hv;
        }
    }
    __syncthreads();
    int lane = t & 63, wave = t >> 6, quad = lane >> 4, l15 = lane & 15;
    bf8 a0 = *(const bf8*)&Hl[wave * 16 + l15][quad * 8];
    bf8 a1 = *(const bf8*)&Hl[wave * 16 + l15][32 + quad * 8];
    for (int m = 0; m < 3; ++m) {
        const float* bias = (m == 0) ? bq : (m == 1) ? bk : bv;
        float sc = (m == 0) ? 0.125f * LOG2E : 1.0f;
        for (int tt = 0; tt < 4; ++tt) {
            int col = l15 + 16 * tt;
            bf8 b0 = *(const bf8*)&W[m][col][quad * 8];
            bf8 b1 = *(const bf8*)&W[m][col][32 + quad * 8];
            f4 acc = {0.f, 0.f, 0.f, 0.f};
            acc = mfma16(a0, b0, acc);
            acc = mfma16(a1, b1, acc);
            float bb = bias[col];
            if (m == 2) {
                for (int r = 0; r < 4; ++r)
                    Vst[col][wave * 16 + quad * 4 + r] = (_Float16)(acc[r] + bb);
            } else {
                __bf16* dst = (m == 0) ? q : k;
                for (int r = 0; r < 4; ++r) {
                    float val = (acc[r] + bb) * sc;
                    dst[(rowbase + wave * 16 + quad * 4 + r) * 64 + col] = (__bf16)val;
                }
            }
        }
    }
    __syncthreads();
    {   // slot-permuted V writeout (two 32-key tiles per block)
        int d = wave * 16 + l15;
        for (int kb = 0; kb < 2; ++kb) {
            h4 lo = *(const h4*)&Vst[d][kb * 32 + quad * 4];
            h4 hi = *(const h4*)&Vst[d][kb * 32 + 16 + quad * 4];
            h8 o;
            o[0] = lo[0]; o[1] = lo[1]; o[2] = lo[2]; o[3] = lo[3];
            o[4] = hi[0]; o[5] = hi[1]; o[6] = hi[2]; o[7] = hi[3];
            _Float16* dst = vT + ((((size_t)b * 128 + (tokbase >> 5) + kb) * 4 + wave) * 64
                                  + lane) * 8;
            *(h8*)dst = o;
        }
    }
}

// ---------------- fused attention + output projection + residual -------------------------
// grid 512 = qt*8 + b; block 512 = 8 waves; wave owns 512 keys = 16 iters x 32 keys.
// TLP fix (this rev): 8 waves/block at grid 512 -> 16 waves/CU = 4 waves/SIMD (was 2),
// same per-block K/V L2 traffic (512 MB total). 3-level pairwise merge tree; epilogue
// split across all 8 waves. VGPR 104 fits 4 waves/SIMD; LDS ~57 KB x 2 blocks < 160 KB.
__device__ __forceinline__ void load_kv(const __bf16* kr0, const _Float16* vr, int quad,
                                        bf8 kf[4], h8 vf[4]) {
    kf[0] = *(const bf8*)(kr0 + quad * 8);
    kf[1] = *(const bf8*)(kr0 + 32 + quad * 8);
    kf[2] = *(const bf8*)(kr0 + 1024 + quad * 8);          // +16*64
    kf[3] = *(const bf8*)(kr0 + 1024 + 32 + quad * 8);
    vf[0] = *(const h8*)(vr);
    vf[1] = *(const h8*)(vr + 512);
    vf[2] = *(const h8*)(vr + 1024);
    vf[3] = *(const h8*)(vr + 1536);
}

__device__ __forceinline__ void compute32(const bf8 kf[4], const h8 vf[4],
                                          const bf8 aq[4][2], h8 ones,
                                          f4 acc[4][4], f4 acc_li[4]) {
#pragma unroll
    for (int s = 0; s < 4; ++s) {
        f4 St0 = {0.f, 0.f, 0.f, 0.f};
        f4 St1 = {0.f, 0.f, 0.f, 0.f};
        St0 = mfma16(kf[0], aq[s][0], St0);
        St0 = mfma16(kf[1], aq[s][1], St0);
        St1 = mfma16(kf[2], aq[s][0], St1);
        St1 = mfma16(kf[3], aq[s][1], St1);
        float p00 = __builtin_amdgcn_exp2f(St0[0]);
        float p01 = __builtin_amdgcn_exp2f(St0[1]);
        float p02 = __builtin_amdgcn_exp2f(St0[2]);
        float p03 = __builtin_amdgcn_exp2f(St0[3]);
        float p10 = __builtin_amdgcn_exp2f(St1[0]);
        float p11 = __builtin_amdgcn_exp2f(St1[1]);
        float p12 = __builtin_amdgcn_exp2f(St1[2]);
        float p13 = __builtin_amdgcn_exp2f(St1[3]);
        h8 pf;
        ((fp16x2*)&pf)[0] = __builtin_amdgcn_cvt_pkrtz(p00, p01);
        ((fp16x2*)&pf)[1] = __builtin_amdgcn_cvt_pkrtz(p02, p03);
        ((fp16x2*)&pf)[2] = __builtin_amdgcn_cvt_pkrtz(p10, p11);
        ((fp16x2*)&pf)[3] = __builtin_amdgcn_cvt_pkrtz(p12, p13);
        acc_li[s] = mfma32h(ones, pf, acc_li[s]);           // row-sum of p (denominator)
        acc[s][0] = mfma32h(vf[0], pf, acc[s][0]);
        acc[s][1] = mfma32h(vf[1], pf, acc[s][1]);
        acc[s][2] = mfma32h(vf[2], pf, acc[s][2]);
        acc[s][3] = mfma32h(vf[3], pf, acc[s][3]);
    }
}

__global__ __launch_bounds__(512, 4) void attn_final(const __bf16* __restrict__ q,
                                                     const __bf16* __restrict__ k,
                                                     const _Float16* __restrict__ vt,
                                                     const __bf16* __restrict__ wpt,
                                                     const float* __restrict__ bp,
                                                     const float* __restrict__ x,
                                                     const float* __restrict__ gpart,
                                                     const float* __restrict__ gamma,
                                                     const float* __restrict__ beta,
                                                     float* __restrict__ out) {
    __shared__ _Float16 Om[4][64][72];
    __shared__ float sS[4][64];
    __shared__ __bf16 Wl[64][72];
    __shared__ __bf16 Ol[64][72];
    __shared__ float red[128];
    __shared__ float sstat[16], sg[64], sb[64];

    int bid = blockIdx.x;
    int qt = bid >> 3, b = bid & 7;
    int t = threadIdx.x, lane = t & 63, w = t >> 6, quad = lane >> 4, l15 = lane & 15;

    if (t < 256) {
        int e = t * 2;
        int row = e >> 3, ch = e & 7;
        *(bf8*)&Wl[row][ch * 8] = *(const bf8*)(wpt + row * 64 + ch * 8);
        row = (e + 1) >> 3; ch = (e + 1) & 7;
        *(bf8*)&Wl[row][ch * 8] = *(const bf8*)(wpt + row * 64 + ch * 8);
    }
    if (t >= 256 && t < 320) { int u = t - 256; sg[u] = gamma[u]; sb[u] = beta[u]; }
    if (t < 64) {
        int gi = t & 7, c = t >> 3;
        const float2* gp = (const float2*)gpart + (size_t)b * 512 + gi;
        float a = 0.f, aa = 0.f;
        for (int p = c * 8; p < c * 8 + 8; ++p) {
            float2 v = gp[(size_t)p * 8];
            a += v.x; aa += v.y;
        }
        red[t * 2] = a; red[t * 2 + 1] = aa;
    }

    const __bf16* qbase = q + ((size_t)b * NTOK + qt * 64) * 64;
    bf8 aq[4][2];
    for (int s = 0; s < 4; ++s) {
        const __bf16* r = qbase + (s * 16 + l15) * 64;
        aq[s][0] = *(const bf8*)(r + quad * 8);
        aq[s][1] = *(const bf8*)(r + 32 + quad * 8);
    }
    const __bf16* kbase   = k  + ((size_t)b * NTOK + w * 512) * 64;
    const _Float16* vbase = vt + (size_t)b * 262144 + (size_t)(w * 16) * 2048 + lane * 8;

    h8 ones;
#pragma unroll
    for (int j = 0; j < 8; ++j) ones[j] = (_Float16)1.f;

    f4 acc[4][4] = {};
    f4 acc_li[4] = {};

    // 2-deep ping-pong software pipeline over 16 key-tiles
    bf8 kfA[4], kfB[4];
    h8 vfA[4], vfB[4];
    load_kv(kbase + (size_t)l15 * 64, vbase, quad, kfA, vfA);
    for (int it = 0; it < 16; it += 2) {
        load_kv(kbase + (size_t)((it + 1) * 32 + l15) * 64,
                vbase + (size_t)(it + 1) * 2048, quad, kfB, vfB);
        __builtin_amdgcn_s_setprio(1);
        compute32(kfA, vfA, aq, ones, acc, acc_li);
        __builtin_amdgcn_s_setprio(0);
        if (it + 2 < 16)
            load_kv(kbase + (size_t)((it + 2) * 32 + l15) * 64,
                    vbase + (size_t)(it + 2) * 2048, quad, kfA, vfA);
        __builtin_amdgcn_s_setprio(1);
        compute32(kfB, vfB, aq, ones, acc, acc_li);
        __builtin_amdgcn_s_setprio(0);
    }

    // denominator per query (identical in all lanes of the quad-group already)
    float li[4];
#pragma unroll
    for (int s = 0; s < 4; ++s) li[s] = acc_li[s][0];

    // ---- 3-level pairwise merge tree (8 waves -> 1) ----
    // level A: waves 4-7 deposit
    if (w >= 4) {
        for (int s = 0; s < 4; ++s) {
            for (int td = 0; td < 4; ++td) {
                h4 o4;
                for (int r = 0; r < 4; ++r) o4[r] = (_Float16)acc[s][td][r];
                *(h4*)&Om[w - 4][s * 16 + l15][td * 16 + quad * 4] = o4;
            }
            if (quad == 0) sS[w - 4][s * 16 + l15] = li[s];
        }
    }
    __syncthreads();
    if (t < 8) {    // GN stats finalize (red visible now)
        float a = 0.f, aa = 0.f;
        for (int c = 0; c < 8; ++c) {
            a  += red[(c * 8 + t) * 2];
            aa += red[(c * 8 + t) * 2 + 1];
        }
        float mean = a * (1.f / 32768.f);
        float var = aa * (1.f / 32768.f) - mean * mean;
        sstat[t * 2 + 0] = mean;
        sstat[t * 2 + 1] = rsqrtf(var + 1e-3f);
    }
    if (w < 4) {    // level A absorb
        for (int s = 0; s < 4; ++s) {
            for (int td = 0; td < 4; ++td) {
                h4 o4 = *(const h4*)&Om[w][s * 16 + l15][td * 16 + quad * 4];
                for (int r = 0; r < 4; ++r) acc[s][td][r] += (float)o4[r];
            }
            li[s] += sS[w][s * 16 + l15];
        }
    }
    __syncthreads();
    // level B: waves 2,3 deposit
    if (w >= 2 && w < 4) {
        for (int s = 0; s < 4; ++s) {
            for (int td = 0; td < 4; ++td) {
                h4 o4;
                for (int r = 0; r < 4; ++r) o4[r] = (_Float16)acc[s][td][r];
                *(h4*)&Om[w - 2][s * 16 + l15][td * 16 + quad * 4] = o4;
            }
            if (quad == 0) sS[w - 2][s * 16 + l15] = li[s];
        }
    }
    __syncthreads();
    if (w < 2) {    // level B absorb
        for (int s = 0; s < 4; ++s) {
            for (int td = 0; td < 4; ++td) {
                h4 o4 = *(const h4*)&Om[w][s * 16 + l15][td * 16 + quad * 4];
                for (int r = 0; r < 4; ++r) acc[s][td][r] += (float)o4[r];
            }
            li[s] += sS[w][s * 16 + l15];
        }
    }
    __syncthreads();
    // level C: waves 0,1 deposit pair-sums
    if (w < 2) {
        for (int s = 0; s < 4; ++s) {
            for (int td = 0; td < 4; ++td) {
                h4 o4;
                for (int r = 0; r < 4; ++r) o4[r] = (_Float16)acc[s][td][r];
                *(h4*)&Om[w][s * 16 + l15][td * 16 + quad * 4] = o4;
            }
            if (quad == 0) sS[w][s * 16 + l15] = li[s];
        }
    }
    __syncthreads();
    {   // final combine + normalize into Ol (bf16): 512 threads, 8 cols each
        int qq = t >> 3, ds = (t & 7) * 8;
        float inv = 1.f / (sS[0][qq] + sS[1][qq]);
        h8 a0 = *(const h8*)&Om[0][qq][ds];
        h8 a1 = *(const h8*)&Om[1][qq][ds];
        bf8 o;
        for (int j = 0; j < 8; ++j)
            o[j] = (__bf16)(((float)a0[j] + (float)a1[j]) * inv);
        *(bf8*)&Ol[qq][ds] = o;
    }
    __syncthreads();
    // epilogue: out = Ol @ wp^T + bp + GN(x); 8 waves: rows (w&3)*16, col-half (w>>2)
    {
        int wr = w & 3, wh = w >> 2;
        size_t rowbase = ((size_t)b * NTOK + qt * 64) + wr * 16;
        bf8 a0 = *(const bf8*)&Ol[wr * 16 + l15][quad * 8];
        bf8 a1 = *(const bf8*)&Ol[wr * 16 + l15][32 + quad * 8];
        for (int tth = 0; tth < 2; ++tth) {
            int tt = wh * 2 + tth;
            int col = l15 + 16 * tt;
            bf8 b0 = *(const bf8*)&Wl[col][quad * 8];
            bf8 b1 = *(const bf8*)&Wl[col][32 + quad * 8];
            f4 pacc = {0.f, 0.f, 0.f, 0.f};
            pacc = mfma16(a0, b0, pacc);
            pacc = mfma16(a1, b1, pacc);
            int grp = col >> 3;
            float mean = sstat[grp * 2], gs = sg[col] * sstat[grp * 2 + 1], bs = sb[col];
            float bias = bp[col];
            for (int r = 0; r < 4; ++r) {
                size_t gi = (rowbase + quad * 4 + r) * 64 + col;
                float h = (x[gi] - mean) * gs + bs;
                out[gi] = pacc[r] + bias + h;
            }
        }
    }
}

extern "C" void kernel_launch(void* const* d_in, const int* in_sizes, int n_in,
                              void* d_out, int out_size, void* d_ws, size_t ws_size,
                              hipStream_t stream) {
    const float* x     = (const float*)d_in[0];
    const float* gamma = (const float*)d_in[1];
    const float* beta  = (const float*)d_in[2];
    const float* wq    = (const float*)d_in[3];
    const float* bq    = (const float*)d_in[4];
    const float* wk    = (const float*)d_in[5];
    const float* bk    = (const float*)d_in[6];
    const float* wv    = (const float*)d_in[7];
    const float* bv    = (const float*)d_in[8];
    const float* wp    = (const float*)d_in[9];
    const float* bp    = (const float*)d_in[10];
    float* out = (float*)d_out;

    char* ws = (char*)d_ws;
    const size_t MB = 1024 * 1024;
    __bf16*   qb   = (__bf16*)(ws);                 // 4 MB
    __bf16*   kb   = (__bf16*)(ws + 4 * MB);        // 4 MB
    _Float16* vtb  = (_Float16*)(ws + 8 * MB);      // 4 MB (slot-permuted V fp16)
    __bf16*   wqt  = (__bf16*)(ws + 12 * MB);
    __bf16*   wkt  = (__bf16*)(ws + 12 * MB + 8192);
    __bf16*   wvt  = (__bf16*)(ws + 12 * MB + 16384);
    __bf16*   wpt  = (__bf16*)(ws + 12 * MB + 24576);
    float*    gpart = (float*)(ws + 12 * MB + 32768);   // 32 KB

    pre_kernel<<<516, 256, 0, stream>>>(wq, wk, wv, wp, x, wqt, wkt, wvt, wpt, gpart);
    qkv_gn<<<512, 256, 0, stream>>>(x, gpart, gamma, beta, wqt, wkt, wvt, bq, bk, bv, qb, kb, vtb);
    attn_final<<<512, 512, 0, stream>>>(qb, kb, vtb, wpt, bp, x, gpart, gamma, beta, out);
}

// Round 4
// 165.376 us; speedup vs baseline: 3.1665x; 3.1665x over previous
//
#include <hip/hip_runtime.h>

#define NTOK 4096
#define CH 64
#define LOG2E 1.4426950408889634f

typedef __bf16 bf8 __attribute__((ext_vector_type(8)));
typedef __bf16 bf4 __attribute__((ext_vector_type(4)));
typedef _Float16 h8 __attribute__((ext_vector_type(8)));
typedef _Float16 h4 __attribute__((ext_vector_type(4)));
typedef __fp16 fp16x2 __attribute__((ext_vector_type(2)));
typedef float f4 __attribute__((ext_vector_type(4)));

__device__ __forceinline__ f4 mfma16(bf8 a, bf8 b, f4 c) {
    return __builtin_amdgcn_mfma_f32_16x16x32_bf16(a, b, c, 0, 0, 0);
}
__device__ __forceinline__ f4 mfma32h(h8 a, h8 b, f4 c) {
    return __builtin_amdgcn_mfma_f32_16x16x32_f16(a, b, c, 0, 0, 0);
}

// ---------------- fused pre-pass: blocks 0..3 = weight transpose; 4..515 = GN partials ----
__global__ __launch_bounds__(256) void pre_kernel(const float* __restrict__ wq,
                                                  const float* __restrict__ wk,
                                                  const float* __restrict__ wv,
                                                  const float* __restrict__ wp,
                                                  const float* __restrict__ x,
                                                  __bf16* __restrict__ wqt,
                                                  __bf16* __restrict__ wkt,
                                                  __bf16* __restrict__ wvt,
                                                  __bf16* __restrict__ wpt,
                                                  float* __restrict__ gpart) {
    int t = threadIdx.x;
    if (blockIdx.x < 4) {   // weight transpose + bf16 convert
        int m = blockIdx.x;
        const float* src = (m == 0) ? wq : (m == 1) ? wk : (m == 2) ? wv : wp;
        __bf16* dst      = (m == 0) ? wqt : (m == 1) ? wkt : (m == 2) ? wvt : wpt;
        __shared__ float s[64][65];
        for (int i = 0; i < 16; ++i) {
            int e = i * 256 + t;
            s[e >> 6][e & 63] = src[e];
        }
        __syncthreads();
        int o = t >> 2, seg = t & 3;
        for (int j = 0; j < 16; ++j) {
            int in = seg * 16 + j;
            dst[o * 64 + in] = (__bf16)s[in][o];
        }
        return;
    }
    // GN partial sums: 512 blocks = 8b x 64 slabs of 64 rows
    int bid = blockIdx.x - 4;
    int b = bid >> 6, slab = bid & 63;
    const float4* xb = (const float4*)(x + (size_t)(b * NTOK + slab * 64) * CH);
    float s = 0.f, ss = 0.f;
    for (int i = 0; i < 4; ++i) {
        int row = (t >> 4) + i * 16;
        float4 v = xb[row * 16 + (t & 15)];
        s  += v.x + v.y + v.z + v.w;
        ss += v.x * v.x + v.y * v.y + v.z * v.z + v.w * v.w;
    }
    __shared__ float ls[256], lss[256];
    ls[t] = s; lss[t] = ss;
    __syncthreads();
    if (t < 8) {
        float a = 0.f, aa = 0.f;
        for (int p = 0; p < 16; ++p) {
            a  += ls[p * 16 + 2 * t]  + ls[p * 16 + 2 * t + 1];
            aa += lss[p * 16 + 2 * t] + lss[p * 16 + 2 * t + 1];
        }
        gpart[((b * 64 + slab) * 8 + t) * 2 + 0] = a;
        gpart[((b * 64 + slab) * 8 + t) * 2 + 1] = aa;
    }
}

// ---------------- fused GN + QKV projection (grid 512, 64 rows/block) --------------------
// V written fp16 in slot-permuted K=32 fragment layout:
//   vt[((b*128 + kt32)*4 + td)*64 + lane] (h8): lane=(quad,l15) holds
//   V^T[d=td*16+l15][slot quad*8+j], slot j<4 -> key quad*4+j ; j>=4 -> 16+quad*4+(j-4)
__global__ __launch_bounds__(256) void qkv_gn(const float* __restrict__ x,
                                              const float* __restrict__ gpart,
                                              const float* __restrict__ gamma,
                                              const float* __restrict__ beta,
                                              const __bf16* __restrict__ wqt,
                                              const __bf16* __restrict__ wkt,
                                              const __bf16* __restrict__ wvt,
                                              const float* __restrict__ bq,
                                              const float* __restrict__ bk,
                                              const float* __restrict__ bv,
                                              __bf16* __restrict__ q,
                                              __bf16* __restrict__ k,
                                              _Float16* __restrict__ vT) {
    __shared__ __bf16 W[3][64][72];
    __shared__ __bf16 Hl[64][72];
    __shared__ _Float16 Vst[64][68];
    __shared__ float red[128];
    __shared__ float sstat[16];
    int t = threadIdx.x;
    size_t rowbase = (size_t)blockIdx.x * 64;
    int b = (int)(rowbase >> 12), tokbase = (int)(rowbase & 4095);
    if (t < 64) {
        int gi = t & 7, c = t >> 3;
        const float2* gp = (const float2*)gpart + (size_t)b * 512 + gi;
        float a = 0.f, aa = 0.f;
        for (int p = c * 8; p < c * 8 + 8; ++p) {
            float2 v = gp[(size_t)p * 8];
            a += v.x; aa += v.y;
        }
        red[t * 2] = a; red[t * 2 + 1] = aa;
    }
    for (int m = 0; m < 3; ++m) {
        const __bf16* src = (m == 0) ? wqt : (m == 1) ? wkt : wvt;
        for (int i = 0; i < 2; ++i) {
            int e = i * 256 + t, row = e >> 3, ch = e & 7;
            *(bf8*)&W[m][row][ch * 8] = *(const bf8*)(src + row * 64 + ch * 8);
        }
    }
    __syncthreads();
    if (t < 8) {
        float a = 0.f, aa = 0.f;
        for (int c = 0; c < 8; ++c) {
            a  += red[(c * 8 + t) * 2];
            aa += red[(c * 8 + t) * 2 + 1];
        }
        float mean = a * (1.f / 32768.f);
        float var = aa * (1.f / 32768.f) - mean * mean;
        sstat[t * 2 + 0] = mean;
        sstat[t * 2 + 1] = rsqrtf(var + 1e-3f);
    }
    __syncthreads();
    {
        int c4 = (t & 15) * 4, grp = c4 >> 3;
        float mean = sstat[grp * 2], rstd = sstat[grp * 2 + 1];
        float g0 = gamma[c4] * rstd, g1 = gamma[c4 + 1] * rstd,
              g2 = gamma[c4 + 2] * rstd, g3 = gamma[c4 + 3] * rstd;
        float b0 = beta[c4], b1 = beta[c4 + 1], b2 = beta[c4 + 2], b3 = beta[c4 + 3];
        const float4* xb = (const float4*)(x + rowbase * 64);
        for (int i = 0; i < 4; ++i) {
            int row = (t >> 4) + i * 16;
            float4 v = xb[row * 16 + (t & 15)];
            bf4 hv;
            hv[0] = (__bf16)((v.x - mean) * g0 + b0);
            hv[1] = (__bf16)((v.y - mean) * g1 + b1);
            hv[2] = (__bf16)((v.z - mean) * g2 + b2);
            hv[3] = (__bf16)((v.w - mean) * g3 + b3);
            *(bf4*)&Hl[row][c4] = hv;
        }
    }
    __syncthreads();
    int lane = t & 63, wave = t >> 6, quad = lane >> 4, l15 = lane & 15;
    bf8 a0 = *(const bf8*)&Hl[wave * 16 + l15][quad * 8];
    bf8 a1 = *(const bf8*)&Hl[wave * 16 + l15][32 + quad * 8];
    for (int m = 0; m < 3; ++m) {
        const float* bias = (m == 0) ? bq : (m == 1) ? bk : bv;
        float sc = (m == 0) ? 0.125f * LOG2E : 1.0f;
        for (int tt = 0; tt < 4; ++tt) {
            int col = l15 + 16 * tt;
            bf8 b0 = *(const bf8*)&W[m][col][quad * 8];
            bf8 b1 = *(const bf8*)&W[m][col][32 + quad * 8];
            f4 acc = {0.f, 0.f, 0.f, 0.f};
            acc = mfma16(a0, b0, acc);
            acc = mfma16(a1, b1, acc);
            float bb = bias[col];
            if (m == 2) {
                for (int r = 0; r < 4; ++r)
                    Vst[col][wave * 16 + quad * 4 + r] = (_Float16)(acc[r] + bb);
            } else {
                __bf16* dst = (m == 0) ? q : k;
                for (int r = 0; r < 4; ++r) {
                    float val = (acc[r] + bb) * sc;
                    dst[(rowbase + wave * 16 + quad * 4 + r) * 64 + col] = (__bf16)val;
                }
            }
        }
    }
    __syncthreads();
    {   // slot-permuted V writeout (two 32-key tiles per block)
        int d = wave * 16 + l15;
        for (int kb = 0; kb < 2; ++kb) {
            h4 lo = *(const h4*)&Vst[d][kb * 32 + quad * 4];
            h4 hi = *(const h4*)&Vst[d][kb * 32 + 16 + quad * 4];
            h8 o;
            o[0] = lo[0]; o[1] = lo[1]; o[2] = lo[2]; o[3] = lo[3];
            o[4] = hi[0]; o[5] = hi[1]; o[6] = hi[2]; o[7] = hi[3];
            _Float16* dst = vT + ((((size_t)b * 128 + (tokbase >> 5) + kb) * 4 + wave) * 64
                                  + lane) * 8;
            *(h8*)dst = o;
        }
    }
}

// ---------------- fused attention + output projection + residual -------------------------
// grid 1024 = qt*8 + b (qt = 128 tiles of 32 q-rows); block 256 = 4 waves; wave owns
// 1024 keys = 32 iters x 32 keys (structure identical to the 51.8us R2 kernel).
// Occupancy fix (this rev): halve the q-tile instead of growing the block ->
// VGPR ~75 (acc[2][4]), LDS ~25 KB -> 4 blocks/CU = 4 waves/SIMD (was 2), no
// launch-bounds clamp (R3's (512,4) caused a 64-VGPR clamp + scratch spills:
// FETCH 770MB). K/V L2 traffic doubles to ~1GB but stays per-XCD L2-resident
// (b = bid&7 keeps each XCD on ~one batch, 1.5MB working set < 4MB L2).
__device__ __forceinline__ void load_kv(const __bf16* kr0, const _Float16* vr, int quad,
                                        bf8 kf[4], h8 vf[4]) {
    kf[0] = *(const bf8*)(kr0 + quad * 8);
    kf[1] = *(const bf8*)(kr0 + 32 + quad * 8);
    kf[2] = *(const bf8*)(kr0 + 1024 + quad * 8);          // +16*64
    kf[3] = *(const bf8*)(kr0 + 1024 + 32 + quad * 8);
    vf[0] = *(const h8*)(vr);
    vf[1] = *(const h8*)(vr + 512);
    vf[2] = *(const h8*)(vr + 1024);
    vf[3] = *(const h8*)(vr + 1536);
}

__device__ __forceinline__ void compute32(const bf8 kf[4], const h8 vf[4],
                                          const bf8 aq[2][2], h8 ones,
                                          f4 acc[2][4], f4 acc_li[2]) {
#pragma unroll
    for (int s = 0; s < 2; ++s) {
        f4 St0 = {0.f, 0.f, 0.f, 0.f};
        f4 St1 = {0.f, 0.f, 0.f, 0.f};
        St0 = mfma16(kf[0], aq[s][0], St0);
        St0 = mfma16(kf[1], aq[s][1], St0);
        St1 = mfma16(kf[2], aq[s][0], St1);
        St1 = mfma16(kf[3], aq[s][1], St1);
        float p00 = __builtin_amdgcn_exp2f(St0[0]);
        float p01 = __builtin_amdgcn_exp2f(St0[1]);
        float p02 = __builtin_amdgcn_exp2f(St0[2]);
        float p03 = __builtin_amdgcn_exp2f(St0[3]);
        float p10 = __builtin_amdgcn_exp2f(St1[0]);
        float p11 = __builtin_amdgcn_exp2f(St1[1]);
        float p12 = __builtin_amdgcn_exp2f(St1[2]);
        float p13 = __builtin_amdgcn_exp2f(St1[3]);
        h8 pf;
        ((fp16x2*)&pf)[0] = __builtin_amdgcn_cvt_pkrtz(p00, p01);
        ((fp16x2*)&pf)[1] = __builtin_amdgcn_cvt_pkrtz(p02, p03);
        ((fp16x2*)&pf)[2] = __builtin_amdgcn_cvt_pkrtz(p10, p11);
        ((fp16x2*)&pf)[3] = __builtin_amdgcn_cvt_pkrtz(p12, p13);
        acc_li[s] = mfma32h(ones, pf, acc_li[s]);           // row-sum of p (denominator)
        acc[s][0] = mfma32h(vf[0], pf, acc[s][0]);
        acc[s][1] = mfma32h(vf[1], pf, acc[s][1]);
        acc[s][2] = mfma32h(vf[2], pf, acc[s][2]);
        acc[s][3] = mfma32h(vf[3], pf, acc[s][3]);
    }
}

__global__ __launch_bounds__(256, 2) void attn_final(const __bf16* __restrict__ q,
                                                     const __bf16* __restrict__ k,
                                                     const _Float16* __restrict__ vt,
                                                     const __bf16* __restrict__ wpt,
                                                     const float* __restrict__ bp,
                                                     const float* __restrict__ x,
                                                     const float* __restrict__ gpart,
                                                     const float* __restrict__ gamma,
                                                     const float* __restrict__ beta,
                                                     float* __restrict__ out) {
    __shared__ _Float16 Om[2][32][72];
    __shared__ float sS[2][32];
    __shared__ __bf16 Wl[64][72];
    __shared__ __bf16 Ol[32][72];
    __shared__ float red[128];
    __shared__ float sstat[16], sg[64], sb[64];

    int bid = blockIdx.x;
    int qt = bid >> 3, b = bid & 7;     // qt in 0..127, 32-row q-tiles
    int t = threadIdx.x, lane = t & 63, w = t >> 6, quad = lane >> 4, l15 = lane & 15;

    for (int i = 0; i < 2; ++i) {
        int e = i * 256 + t, row = e >> 3, ch = e & 7;
        *(bf8*)&Wl[row][ch * 8] = *(const bf8*)(wpt + row * 64 + ch * 8);
    }
    if (t < 64) { sg[t] = gamma[t]; sb[t] = beta[t]; }
    if (t < 64) {
        int gi = t & 7, c = t >> 3;
        const float2* gp = (const float2*)gpart + (size_t)b * 512 + gi;
        float a = 0.f, aa = 0.f;
        for (int p = c * 8; p < c * 8 + 8; ++p) {
            float2 v = gp[(size_t)p * 8];
            a += v.x; aa += v.y;
        }
        red[t * 2] = a; red[t * 2 + 1] = aa;
    }

    const __bf16* qbase = q + ((size_t)b * NTOK + qt * 32) * 64;
    bf8 aq[2][2];
    for (int s = 0; s < 2; ++s) {
        const __bf16* r = qbase + (s * 16 + l15) * 64;
        aq[s][0] = *(const bf8*)(r + quad * 8);
        aq[s][1] = *(const bf8*)(r + 32 + quad * 8);
    }
    const __bf16* kbase   = k  + ((size_t)b * NTOK + w * 1024) * 64;
    const _Float16* vbase = vt + (size_t)b * 262144 + (size_t)(w * 32) * 2048 + lane * 8;

    h8 ones;
#pragma unroll
    for (int j = 0; j < 8; ++j) ones[j] = (_Float16)1.f;

    f4 acc[2][4] = {};
    f4 acc_li[2] = {};

    // 2-deep ping-pong software pipeline over 32 key-tiles
    bf8 kfA[4], kfB[4];
    h8 vfA[4], vfB[4];
    load_kv(kbase + (size_t)l15 * 64, vbase, quad, kfA, vfA);
    for (int it = 0; it < 32; it += 2) {
        load_kv(kbase + (size_t)((it + 1) * 32 + l15) * 64,
                vbase + (size_t)(it + 1) * 2048, quad, kfB, vfB);
        __builtin_amdgcn_s_setprio(1);
        compute32(kfA, vfA, aq, ones, acc, acc_li);
        __builtin_amdgcn_s_setprio(0);
        if (it + 2 < 32)
            load_kv(kbase + (size_t)((it + 2) * 32 + l15) * 64,
                    vbase + (size_t)(it + 2) * 2048, quad, kfA, vfA);
        __builtin_amdgcn_s_setprio(1);
        compute32(kfB, vfB, aq, ones, acc, acc_li);
        __builtin_amdgcn_s_setprio(0);
    }

    // denominator per query (identical in all lanes of the quad-group already)
    float li[2];
#pragma unroll
    for (int s = 0; s < 2; ++s) li[s] = acc_li[s][0];

    // 3-phase pairwise merge (4 waves -> 1)
    if (w >= 2) {   // phase 1: waves 2,3 deposit
        for (int s = 0; s < 2; ++s) {
            for (int td = 0; td < 4; ++td) {
                h4 o4;
                for (int r = 0; r < 4; ++r) o4[r] = (_Float16)acc[s][td][r];
                *(h4*)&Om[w - 2][s * 16 + l15][td * 16 + quad * 4] = o4;
            }
            if (quad == 0) sS[w - 2][s * 16 + l15] = li[s];
        }
    }
    __syncthreads();
    if (t < 8) {    // GN stats finalize (red visible now)
        float a = 0.f, aa = 0.f;
        for (int c = 0; c < 8; ++c) {
            a  += red[(c * 8 + t) * 2];
            aa += red[(c * 8 + t) * 2 + 1];
        }
        float mean = a * (1.f / 32768.f);
        float var = aa * (1.f / 32768.f) - mean * mean;
        sstat[t * 2 + 0] = mean;
        sstat[t * 2 + 1] = rsqrtf(var + 1e-3f);
    }
    if (w < 2) {    // waves 0,1 absorb
        for (int s = 0; s < 2; ++s) {
            for (int td = 0; td < 4; ++td) {
                h4 o4 = *(const h4*)&Om[w][s * 16 + l15][td * 16 + quad * 4];
                for (int r = 0; r < 4; ++r) acc[s][td][r] += (float)o4[r];
            }
            li[s] += sS[w][s * 16 + l15];
        }
    }
    __syncthreads();
    if (w < 2) {    // phase 2: deposit pair-sums
        for (int s = 0; s < 2; ++s) {
            for (int td = 0; td < 4; ++td) {
                h4 o4;
                for (int r = 0; r < 4; ++r) o4[r] = (_Float16)acc[s][td][r];
                *(h4*)&Om[w][s * 16 + l15][td * 16 + quad * 4] = o4;
            }
            if (quad == 0) sS[w][s * 16 + l15] = li[s];
        }
    }
    __syncthreads();
    {   // phase 3: combine + normalize into Ol (bf16): 256 threads = 32 rows x 8 col-segs
        int qq = t >> 3, ds = (t & 7) * 8;
        float inv = 1.f / (sS[0][qq] + sS[1][qq]);
        h8 a0 = *(const h8*)&Om[0][qq][ds];
        h8 a1 = *(const h8*)&Om[1][qq][ds];
        bf8 o;
        for (int j = 0; j < 8; ++j)
            o[j] = (__bf16)(((float)a0[j] + (float)a1[j]) * inv);
        *(bf8*)&Ol[qq][ds] = o;
    }
    __syncthreads();
    // epilogue: out = Ol @ wp^T + bp + GN(x); wave w: rows (w&1)*16, col-half (w>>1)*32
    {
        int wr = w & 1, wh = w >> 1;
        size_t rowbase = ((size_t)b * NTOK + qt * 32) + wr * 16;
        bf8 a0 = *(const bf8*)&Ol[wr * 16 + l15][quad * 8];
        bf8 a1 = *(const bf8*)&Ol[wr * 16 + l15][32 + quad * 8];
        for (int tth = 0; tth < 2; ++tth) {
            int tt = wh * 2 + tth;
            int col = l15 + 16 * tt;
            bf8 b0 = *(const bf8*)&Wl[col][quad * 8];
            bf8 b1 = *(const bf8*)&Wl[col][32 + quad * 8];
            f4 pacc = {0.f, 0.f, 0.f, 0.f};
            pacc = mfma16(a0, b0, pacc);
            pacc = mfma16(a1, b1, pacc);
            int grp = col >> 3;
            float mean = sstat[grp * 2], gs = sg[col] * sstat[grp * 2 + 1], bs = sb[col];
            float bias = bp[col];
            for (int r = 0; r < 4; ++r) {
                size_t gi = (rowbase + quad * 4 + r) * 64 + col;
                float h = (x[gi] - mean) * gs + bs;
                out[gi] = pacc[r] + bias + h;
            }
        }
    }
}

extern "C" void kernel_launch(void* const* d_in, const int* in_sizes, int n_in,
                              void* d_out, int out_size, void* d_ws, size_t ws_size,
                              hipStream_t stream) {
    const float* x     = (const float*)d_in[0];
    const float* gamma = (const float*)d_in[1];
    const float* beta  = (const float*)d_in[2];
    const float* wq    = (const float*)d_in[3];
    const float* bq    = (const float*)d_in[4];
    const float* wk    = (const float*)d_in[5];
    const float* bk    = (const float*)d_in[6];
    const float* wv    = (const float*)d_in[7];
    const float* bv    = (const float*)d_in[8];
    const float* wp    = (const float*)d_in[9];
    const float* bp    = (const float*)d_in[10];
    float* out = (float*)d_out;

    char* ws = (char*)d_ws;
    const size_t MB = 1024 * 1024;
    __bf16*   qb   = (__bf16*)(ws);                 // 4 MB
    __bf16*   kb   = (__bf16*)(ws + 4 * MB);        // 4 MB
    _Float16* vtb  = (_Float16*)(ws + 8 * MB);      // 4 MB (slot-permuted V fp16)
    __bf16*   wqt  = (__bf16*)(ws + 12 * MB);
    __bf16*   wkt  = (__bf16*)(ws + 12 * MB + 8192);
    __bf16*   wvt  = (__bf16*)(ws + 12 * MB + 16384);
    __bf16*   wpt  = (__bf16*)(ws + 12 * MB + 24576);
    float*    gpart = (float*)(ws + 12 * MB + 32768);   // 32 KB

    pre_kernel<<<516, 256, 0, stream>>>(wq, wk, wv, wp, x, wqt, wkt, wvt, wpt, gpart);
    qkv_gn<<<512, 256, 0, stream>>>(x, gpart, gamma, beta, wqt, wkt, wvt, bq, bk, bv, qb, kb, vtb);
    attn_final<<<1024, 256, 0, stream>>>(qb, kb, vtb, wpt, bp, x, gpart, gamma, beta, out);
}

// Round 5
// 120.738 us; speedup vs baseline: 4.3372x; 1.3697x over previous
//
#include <hip/hip_runtime.h>

#define NTOK 4096
#define CH 64
#define LOG2E 1.4426950408889634f
#define QK_SCALE 0.42466090014400953f   // sqrt(0.125 * log2(e)) folded into both q and k

typedef __bf16 bf8 __attribute__((ext_vector_type(8)));
typedef __bf16 bf4 __attribute__((ext_vector_type(4)));
typedef _Float16 h8 __attribute__((ext_vector_type(8)));
typedef _Float16 h4 __attribute__((ext_vector_type(4)));
typedef float f4 __attribute__((ext_vector_type(4)));
typedef long lx2 __attribute__((ext_vector_type(2)));   // 16B vector load

__device__ __forceinline__ f4 mfma16(bf8 a, bf8 b, f4 c) {
    return __builtin_amdgcn_mfma_f32_16x16x32_bf16(a, b, c, 0, 0, 0);
}
__device__ __forceinline__ f4 mfma8(long a, long b, f4 c) {
    return __builtin_amdgcn_mfma_f32_16x16x32_fp8_fp8(a, b, c, 0, 0, 0);
}
__device__ __forceinline__ unsigned char to_fp8(float v) {
    return (unsigned char)(__builtin_amdgcn_cvt_pk_fp8_f32(v, v, 0, false) & 0xff);
}

// ---------------- fused pre-pass: blocks 0..3 = weight transpose; 4..515 = GN partials ----
__global__ __launch_bounds__(256) void pre_kernel(const float* __restrict__ wq,
                                                  const float* __restrict__ wk,
                                                  const float* __restrict__ wv,
                                                  const float* __restrict__ wp,
                                                  const float* __restrict__ x,
                                                  __bf16* __restrict__ wqt,
                                                  __bf16* __restrict__ wkt,
                                                  __bf16* __restrict__ wvt,
                                                  __bf16* __restrict__ wpt,
                                                  float* __restrict__ gpart) {
    int t = threadIdx.x;
    if (blockIdx.x < 4) {   // weight transpose + bf16 convert
        int m = blockIdx.x;
        const float* src = (m == 0) ? wq : (m == 1) ? wk : (m == 2) ? wv : wp;
        __bf16* dst      = (m == 0) ? wqt : (m == 1) ? wkt : (m == 2) ? wvt : wpt;
        __shared__ float s[64][65];
        for (int i = 0; i < 16; ++i) {
            int e = i * 256 + t;
            s[e >> 6][e & 63] = src[e];
        }
        __syncthreads();
        int o = t >> 2, seg = t & 3;
        for (int j = 0; j < 16; ++j) {
            int in = seg * 16 + j;
            dst[o * 64 + in] = (__bf16)s[in][o];
        }
        return;
    }
    // GN partial sums: 512 blocks = 8b x 64 slabs of 64 rows
    int bid = blockIdx.x - 4;
    int b = bid >> 6, slab = bid & 63;
    const float4* xb = (const float4*)(x + (size_t)(b * NTOK + slab * 64) * CH);
    float s = 0.f, ss = 0.f;
    for (int i = 0; i < 4; ++i) {
        int row = (t >> 4) + i * 16;
        float4 v = xb[row * 16 + (t & 15)];
        s  += v.x + v.y + v.z + v.w;
        ss += v.x * v.x + v.y * v.y + v.z * v.z + v.w * v.w;
    }
    __shared__ float ls[256], lss[256];
    ls[t] = s; lss[t] = ss;
    __syncthreads();
    if (t < 8) {
        float a = 0.f, aa = 0.f;
        for (int p = 0; p < 16; ++p) {
            a  += ls[p * 16 + 2 * t]  + ls[p * 16 + 2 * t + 1];
            aa += lss[p * 16 + 2 * t] + lss[p * 16 + 2 * t + 1];
        }
        gpart[((b * 64 + slab) * 8 + t) * 2 + 0] = a;
        gpart[((b * 64 + slab) * 8 + t) * 2 + 1] = aa;
    }
}

// ---------------- fused GN + QKV projection (grid 512, 64 rows/block) --------------------
// Outputs (all fp8 e4m3, packed fragment layouts to minimize attn VMEM instructions):
//  qf : row-major [tok][64] fp8, values scaled by QK_SCALE
//  kp : [b][tile16 (256)][lane64][16B]  lane=(quad,l15): bytes0-7 = K[tile*16+l15][quad*8..]
//       bytes8-15 = K[tile*16+l15][32+quad*8..]  (scaled by QK_SCALE)
//  vp : [b][kt32 (128)][chunk2][lane64][16B] chunk c: bytes0-7 = td=2c A-frag, 8-15 = td=2c+1
//       td A-frag: lane(quad,l15) holds V^T[d=td*16+l15][slot quad*8+j],
//       slot j<4 -> key quad*4+j ; j>=4 -> 16+quad*4+(j-4)
__global__ __launch_bounds__(256) void qkv_gn(const float* __restrict__ x,
                                              const float* __restrict__ gpart,
                                              const float* __restrict__ gamma,
                                              const float* __restrict__ beta,
                                              const __bf16* __restrict__ wqt,
                                              const __bf16* __restrict__ wkt,
                                              const __bf16* __restrict__ wvt,
                                              const float* __restrict__ bq,
                                              const float* __restrict__ bk,
                                              const float* __restrict__ bv,
                                              unsigned char* __restrict__ qf,
                                              unsigned char* __restrict__ kp,
                                              unsigned char* __restrict__ vp) {
    __shared__ __bf16 W[3][64][72];
    __shared__ __bf16 Hl[64][72];
    __shared__ _Float16 Vst[64][68];
    __shared__ unsigned char Kst[64][72];
    __shared__ float red[128];
    __shared__ float sstat[16];
    int t = threadIdx.x;
    size_t rowbase = (size_t)blockIdx.x * 64;
    int b = (int)(rowbase >> 12), tokbase = (int)(rowbase & 4095);
    if (t < 64) {
        int gi = t & 7, c = t >> 3;
        const float2* gp = (const float2*)gpart + (size_t)b * 512 + gi;
        float a = 0.f, aa = 0.f;
        for (int p = c * 8; p < c * 8 + 8; ++p) {
            float2 v = gp[(size_t)p * 8];
            a += v.x; aa += v.y;
        }
        red[t * 2] = a; red[t * 2 + 1] = aa;
    }
    for (int m = 0; m < 3; ++m) {
        const __bf16* src = (m == 0) ? wqt : (m == 1) ? wkt : wvt;
        for (int i = 0; i < 2; ++i) {
            int e = i * 256 + t, row = e >> 3, ch = e & 7;
            *(bf8*)&W[m][row][ch * 8] = *(const bf8*)(src + row * 64 + ch * 8);
        }
    }
    __syncthreads();
    if (t < 8) {
        float a = 0.f, aa = 0.f;
        for (int c = 0; c < 8; ++c) {
            a  += red[(c * 8 + t) * 2];
            aa += red[(c * 8 + t) * 2 + 1];
        }
        float mean = a * (1.f / 32768.f);
        float var = aa * (1.f / 32768.f) - mean * mean;
        sstat[t * 2 + 0] = mean;
        sstat[t * 2 + 1] = rsqrtf(var + 1e-3f);
    }
    __syncthreads();
    {
        int c4 = (t & 15) * 4, grp = c4 >> 3;
        float mean = sstat[grp * 2], rstd = sstat[grp * 2 + 1];
        float g0 = gamma[c4] * rstd, g1 = gamma[c4 + 1] * rstd,
              g2 = gamma[c4 + 2] * rstd, g3 = gamma[c4 + 3] * rstd;
        float b0 = beta[c4], b1 = beta[c4 + 1], b2 = beta[c4 + 2], b3 = beta[c4 + 3];
        const float4* xb = (const float4*)(x + rowbase * 64);
        for (int i = 0; i < 4; ++i) {
            int row = (t >> 4) + i * 16;
            float4 v = xb[row * 16 + (t & 15)];
            bf4 hv;
            hv[0] = (__bf16)((v.x - mean) * g0 + b0);
            hv[1] = (__bf16)((v.y - mean) * g1 + b1);
            hv[2] = (__bf16)((v.z - mean) * g2 + b2);
            hv[3] = (__bf16)((v.w - mean) * g3 + b3);
            *(bf4*)&Hl[row][c4] = hv;
        }
    }
    __syncthreads();
    int lane = t & 63, wave = t >> 6, quad = lane >> 4, l15 = lane & 15;
    bf8 a0 = *(const bf8*)&Hl[wave * 16 + l15][quad * 8];
    bf8 a1 = *(const bf8*)&Hl[wave * 16 + l15][32 + quad * 8];
    for (int m = 0; m < 3; ++m) {
        const float* bias = (m == 0) ? bq : (m == 1) ? bk : bv;
        float sc = (m == 2) ? 1.0f : QK_SCALE;
        for (int tt = 0; tt < 4; ++tt) {
            int col = l15 + 16 * tt;
            bf8 b0 = *(const bf8*)&W[m][col][quad * 8];
            bf8 b1 = *(const bf8*)&W[m][col][32 + quad * 8];
            f4 acc = {0.f, 0.f, 0.f, 0.f};
            acc = mfma16(a0, b0, acc);
            acc = mfma16(a1, b1, acc);
            float bb = bias[col];
            if (m == 2) {
                for (int r = 0; r < 4; ++r)
                    Vst[col][wave * 16 + quad * 4 + r] = (_Float16)(acc[r] + bb);
            } else if (m == 1) {
                for (int r = 0; r < 4; ++r)
                    Kst[wave * 16 + quad * 4 + r][col] = to_fp8((acc[r] + bb) * sc);
            } else {
                for (int r = 0; r < 4; ++r) {
                    float val = (acc[r] + bb) * sc;
                    qf[(rowbase + wave * 16 + quad * 4 + r) * 64 + col] = to_fp8(val);
                }
            }
        }
    }
    __syncthreads();
    {   // packed fp8 K writeout: wave = key16-tile index within block
        const unsigned char* row = &Kst[wave * 16 + l15][0];
        long lo = *(const long*)(row + quad * 8);
        long hi = *(const long*)(row + 32 + quad * 8);
        lx2 kk; kk[0] = lo; kk[1] = hi;
        *(lx2*)(kp + (((size_t)b * 256 + (tokbase >> 4) + wave) * 64 + lane) * 16) = kk;
    }
    {   // packed fp8 V writeout (wave = td): two 32-key tiles per block
        int d = wave * 16 + l15;
        for (int kb = 0; kb < 2; ++kb) {
            h4 lo = *(const h4*)&Vst[d][kb * 32 + quad * 4];
            h4 hi = *(const h4*)&Vst[d][kb * 32 + 16 + quad * 4];
            int d0 = __builtin_amdgcn_cvt_pk_fp8_f32((float)lo[0], (float)lo[1], 0, false);
            d0     = __builtin_amdgcn_cvt_pk_fp8_f32((float)lo[2], (float)lo[3], d0, true);
            int d1 = __builtin_amdgcn_cvt_pk_fp8_f32((float)hi[0], (float)hi[1], 0, false);
            d1     = __builtin_amdgcn_cvt_pk_fp8_f32((float)hi[2], (float)hi[3], d1, true);
            long v8 = (long)(unsigned int)d0 | ((long)d1 << 32);
            int kt = (tokbase >> 5) + kb;
            *(long*)(vp + ((((size_t)b * 128 + kt) * 2 + (wave >> 1)) * 64 + lane) * 16
                        + (wave & 1) * 8) = v8;
        }
    }
}

// ---------------- fused attention + output projection + residual -------------------------
// grid 512 = qt*8 + b; block 256 = 4 waves; wave owns 1024 keys = 32 iters x 32 keys.
// fp8 rev: per 32-key iter only 4 x 16B/lane contiguous loads (2 packed K tiles + 2 packed
// V chunks) vs 8 in bf16 -- targets the measured ~40cyc/VMEM-instr serial cost (additive
// model fit across R0/R2/R4). MFMA count unchanged (fp8 16x16x32 = bf16 shape/rate).
__device__ __forceinline__ void load_kv(const unsigned char* kpw, const unsigned char* vpw,
                                        long kf[4], long vf[4]) {
    lx2 a = *(const lx2*)(kpw);
    lx2 b = *(const lx2*)(kpw + 1024);
    lx2 c = *(const lx2*)(vpw);
    lx2 d = *(const lx2*)(vpw + 1024);
    kf[0] = a[0]; kf[1] = a[1]; kf[2] = b[0]; kf[3] = b[1];
    vf[0] = c[0]; vf[1] = c[1]; vf[2] = d[0]; vf[3] = d[1];
}

__device__ __forceinline__ void compute32(const long kf[4], const long vf[4],
                                          const long aqlo[4], const long aqhi[4],
                                          long ones, f4 acc[4][4], f4 acc_li[4]) {
#pragma unroll
    for (int s = 0; s < 4; ++s) {
        f4 St0 = {0.f, 0.f, 0.f, 0.f};
        f4 St1 = {0.f, 0.f, 0.f, 0.f};
        St0 = mfma8(kf[0], aqlo[s], St0);
        St0 = mfma8(kf[1], aqhi[s], St0);
        St1 = mfma8(kf[2], aqlo[s], St1);
        St1 = mfma8(kf[3], aqhi[s], St1);
        float p00 = __builtin_amdgcn_exp2f(St0[0]);
        float p01 = __builtin_amdgcn_exp2f(St0[1]);
        float p02 = __builtin_amdgcn_exp2f(St0[2]);
        float p03 = __builtin_amdgcn_exp2f(St0[3]);
        float p10 = __builtin_amdgcn_exp2f(St1[0]);
        float p11 = __builtin_amdgcn_exp2f(St1[1]);
        float p12 = __builtin_amdgcn_exp2f(St1[2]);
        float p13 = __builtin_amdgcn_exp2f(St1[3]);
        int d0 = __builtin_amdgcn_cvt_pk_fp8_f32(p00, p01, 0, false);
        d0     = __builtin_amdgcn_cvt_pk_fp8_f32(p02, p03, d0, true);
        int d1 = __builtin_amdgcn_cvt_pk_fp8_f32(p10, p11, 0, false);
        d1     = __builtin_amdgcn_cvt_pk_fp8_f32(p12, p13, d1, true);
        long pf = (long)(unsigned int)d0 | ((long)d1 << 32);
        acc_li[s] = mfma8(ones, pf, acc_li[s]);             // row-sum of p (denominator)
        acc[s][0] = mfma8(vf[0], pf, acc[s][0]);
        acc[s][1] = mfma8(vf[1], pf, acc[s][1]);
        acc[s][2] = mfma8(vf[2], pf, acc[s][2]);
        acc[s][3] = mfma8(vf[3], pf, acc[s][3]);
    }
}

__global__ __launch_bounds__(256, 2) void attn_final(const unsigned char* __restrict__ qf,
                                                     const unsigned char* __restrict__ kp,
                                                     const unsigned char* __restrict__ vp,
                                                     const __bf16* __restrict__ wpt,
                                                     const float* __restrict__ bp,
                                                     const float* __restrict__ x,
                                                     const float* __restrict__ gpart,
                                                     const float* __restrict__ gamma,
                                                     const float* __restrict__ beta,
                                                     float* __restrict__ out) {
    __shared__ _Float16 Om[2][64][72];
    __shared__ float sS[2][64];
    __shared__ __bf16 Wl[64][72];
    __shared__ __bf16 Ol[64][72];
    __shared__ float red[128];
    __shared__ float sstat[16], sg[64], sb[64];

    int bid = blockIdx.x;
    int qt = bid >> 3, b = bid & 7;
    int t = threadIdx.x, lane = t & 63, w = t >> 6, quad = lane >> 4, l15 = lane & 15;

    for (int i = 0; i < 2; ++i) {
        int e = i * 256 + t, row = e >> 3, ch = e & 7;
        *(bf8*)&Wl[row][ch * 8] = *(const bf8*)(wpt + row * 64 + ch * 8);
    }
    if (t < 64) { sg[t] = gamma[t]; sb[t] = beta[t]; }
    if (t < 64) {
        int gi = t & 7, c = t >> 3;
        const float2* gp = (const float2*)gpart + (size_t)b * 512 + gi;
        float a = 0.f, aa = 0.f;
        for (int p = c * 8; p < c * 8 + 8; ++p) {
            float2 v = gp[(size_t)p * 8];
            a += v.x; aa += v.y;
        }
        red[t * 2] = a; red[t * 2 + 1] = aa;
    }

    const unsigned char* qbase = qf + ((size_t)b * NTOK + qt * 64) * 64;
    long aqlo[4], aqhi[4];
    for (int s = 0; s < 4; ++s) {
        const unsigned char* r = qbase + (size_t)(s * 16 + l15) * 64;
        aqlo[s] = *(const long*)(r + quad * 8);
        aqhi[s] = *(const long*)(r + 32 + quad * 8);
    }
    const unsigned char* kpw = kp + ((size_t)b * 256 + w * 64) * 1024 + lane * 16;
    const unsigned char* vpw = vp + ((size_t)b * 128 + w * 32) * 2048 + lane * 16;

    const long ones = 0x3838383838383838L;   // 8 x e4m3(1.0)

    f4 acc[4][4] = {};
    f4 acc_li[4] = {};

    // 2-deep ping-pong software pipeline over 32 key-tiles (4 loads/iter)
    long kfA[4], kfB[4], vfA[4], vfB[4];
    load_kv(kpw, vpw, kfA, vfA);
    for (int it = 0; it < 32; it += 2) {
        load_kv(kpw + (size_t)(it + 1) * 2048, vpw + (size_t)(it + 1) * 2048, kfB, vfB);
        __builtin_amdgcn_s_setprio(1);
        compute32(kfA, vfA, aqlo, aqhi, ones, acc, acc_li);
        __builtin_amdgcn_s_setprio(0);
        if (it + 2 < 32)
            load_kv(kpw + (size_t)(it + 2) * 2048, vpw + (size_t)(it + 2) * 2048, kfA, vfA);
        __builtin_amdgcn_s_setprio(1);
        compute32(kfB, vfB, aqlo, aqhi, ones, acc, acc_li);
        __builtin_amdgcn_s_setprio(0);
    }

    // denominator per query (identical in all lanes of the quad-group already)
    float li[4];
#pragma unroll
    for (int s = 0; s < 4; ++s) li[s] = acc_li[s][0];

    // 3-phase pairwise merge (18.9 KB of merge LDS)
    if (w >= 2) {   // phase 1: waves 2,3 deposit
        for (int s = 0; s < 4; ++s) {
            for (int td = 0; td < 4; ++td) {
                h4 o4;
                for (int r = 0; r < 4; ++r) o4[r] = (_Float16)acc[s][td][r];
                *(h4*)&Om[w - 2][s * 16 + l15][td * 16 + quad * 4] = o4;
            }
            if (quad == 0) sS[w - 2][s * 16 + l15] = li[s];
        }
    }
    __syncthreads();
    if (t < 8) {    // GN stats finalize (red visible now)
        float a = 0.f, aa = 0.f;
        for (int c = 0; c < 8; ++c) {
            a  += red[(c * 8 + t) * 2];
            aa += red[(c * 8 + t) * 2 + 1];
        }
        float mean = a * (1.f / 32768.f);
        float var = aa * (1.f / 32768.f) - mean * mean;
        sstat[t * 2 + 0] = mean;
        sstat[t * 2 + 1] = rsqrtf(var + 1e-3f);
    }
    if (w < 2) {    // waves 0,1 absorb
        for (int s = 0; s < 4; ++s) {
            for (int td = 0; td < 4; ++td) {
                h4 o4 = *(const h4*)&Om[w][s * 16 + l15][td * 16 + quad * 4];
                for (int r = 0; r < 4; ++r) acc[s][td][r] += (float)o4[r];
            }
            li[s] += sS[w][s * 16 + l15];
        }
    }
    __syncthreads();
    if (w < 2) {    // phase 2: deposit pair-sums
        for (int s = 0; s < 4; ++s) {
            for (int td = 0; td < 4; ++td) {
                h4 o4;
                for (int r = 0; r < 4; ++r) o4[r] = (_Float16)acc[s][td][r];
                *(h4*)&Om[w][s * 16 + l15][td * 16 + quad * 4] = o4;
            }
            if (quad == 0) sS[w][s * 16 + l15] = li[s];
        }
    }
    __syncthreads();
    {   // phase 3: combine + normalize into Ol (bf16)
        int qq = t >> 2, ds = (t & 3) * 16;
        float inv = 1.f / (sS[0][qq] + sS[1][qq]);
        h8 a0 = *(const h8*)&Om[0][qq][ds];
        h8 b0 = *(const h8*)&Om[0][qq][ds + 8];
        h8 a1 = *(const h8*)&Om[1][qq][ds];
        h8 b1 = *(const h8*)&Om[1][qq][ds + 8];
        bf8 olo, ohi;
        for (int j = 0; j < 8; ++j) {
            olo[j] = (__bf16)(((float)a0[j] + (float)a1[j]) * inv);
            ohi[j] = (__bf16)(((float)b0[j] + (float)b1[j]) * inv);
        }
        *(bf8*)&Ol[qq][ds] = olo;
        *(bf8*)&Ol[qq][ds + 8] = ohi;
    }
    __syncthreads();
    // epilogue: out = Ol @ wp^T + bp + GN(x)
    size_t rowbase = ((size_t)b * NTOK + qt * 64) + w * 16;
    bf8 a0 = *(const bf8*)&Ol[w * 16 + l15][quad * 8];
    bf8 a1 = *(const bf8*)&Ol[w * 16 + l15][32 + quad * 8];
    for (int tt = 0; tt < 4; ++tt) {
        int col = l15 + 16 * tt;
        bf8 b0 = *(const bf8*)&Wl[col][quad * 8];
        bf8 b1 = *(const bf8*)&Wl[col][32 + quad * 8];
        f4 pacc = {0.f, 0.f, 0.f, 0.f};
        pacc = mfma16(a0, b0, pacc);
        pacc = mfma16(a1, b1, pacc);
        int grp = col >> 3;
        float mean = sstat[grp * 2], gs = sg[col] * sstat[grp * 2 + 1], bs = sb[col];
        float bias = bp[col];
        for (int r = 0; r < 4; ++r) {
            size_t gi = (rowbase + quad * 4 + r) * 64 + col;
            float h = (x[gi] - mean) * gs + bs;
            out[gi] = pacc[r] + bias + h;
        }
    }
}

extern "C" void kernel_launch(void* const* d_in, const int* in_sizes, int n_in,
                              void* d_out, int out_size, void* d_ws, size_t ws_size,
                              hipStream_t stream) {
    const float* x     = (const float*)d_in[0];
    const float* gamma = (const float*)d_in[1];
    const float* beta  = (const float*)d_in[2];
    const float* wq    = (const float*)d_in[3];
    const float* bq    = (const float*)d_in[4];
    const float* wk    = (const float*)d_in[5];
    const float* bk    = (const float*)d_in[6];
    const float* wv    = (const float*)d_in[7];
    const float* bv    = (const float*)d_in[8];
    const float* wp    = (const float*)d_in[9];
    const float* bp    = (const float*)d_in[10];
    float* out = (float*)d_out;

    char* ws = (char*)d_ws;
    const size_t MB = 1024 * 1024;
    unsigned char* qfb = (unsigned char*)(ws);            // 2 MB fp8 Q row-major
    unsigned char* kpb = (unsigned char*)(ws + 2 * MB);   // 2 MB fp8 K packed tiles
    unsigned char* vpb = (unsigned char*)(ws + 4 * MB);   // 2 MB fp8 V packed chunks
    __bf16*   wqt  = (__bf16*)(ws + 12 * MB);
    __bf16*   wkt  = (__bf16*)(ws + 12 * MB + 8192);
    __bf16*   wvt  = (__bf16*)(ws + 12 * MB + 16384);
    __bf16*   wpt  = (__bf16*)(ws + 12 * MB + 24576);
    float*    gpart = (float*)(ws + 12 * MB + 32768);     // 32 KB

    pre_kernel<<<516, 256, 0, stream>>>(wq, wk, wv, wp, x, wqt, wkt, wvt, wpt, gpart);
    qkv_gn<<<512, 256, 0, stream>>>(x, gpart, gamma, beta, wqt, wkt, wvt, bq, bk, bv,
                                    qfb, kpb, vpb);
    attn_final<<<512, 256, 0, stream>>>(qfb, kpb, vpb, wpt, bp, x, gpart, gamma, beta, out);
}

// Round 6
// 118.627 us; speedup vs baseline: 4.4144x; 1.0178x over previous
//
#include <hip/hip_runtime.h>

#define NTOK 4096
#define CH 64
#define LOG2E 1.4426950408889634f
#define QK_SCALE 0.42466090014400953f   // sqrt(0.125 * log2(e)) folded into both q and k

typedef __bf16 bf8 __attribute__((ext_vector_type(8)));
typedef __bf16 bf4 __attribute__((ext_vector_type(4)));
typedef _Float16 h8 __attribute__((ext_vector_type(8)));
typedef _Float16 h4 __attribute__((ext_vector_type(4)));
typedef float f4 __attribute__((ext_vector_type(4)));
typedef long lx2 __attribute__((ext_vector_type(2)));   // 16B vector load

__device__ __forceinline__ f4 mfma16(bf8 a, bf8 b, f4 c) {
    return __builtin_amdgcn_mfma_f32_16x16x32_bf16(a, b, c, 0, 0, 0);
}
__device__ __forceinline__ f4 mfma8(long a, long b, f4 c) {
    return __builtin_amdgcn_mfma_f32_16x16x32_fp8_fp8(a, b, c, 0, 0, 0);
}
__device__ __forceinline__ unsigned char to_fp8(float v) {
    return (unsigned char)(__builtin_amdgcn_cvt_pk_fp8_f32(v, v, 0, false) & 0xff);
}

// ---------------- fused pre-pass: blocks 0..3 = weight transpose; 4..515 = GN partials ----
__global__ __launch_bounds__(256) void pre_kernel(const float* __restrict__ wq,
                                                  const float* __restrict__ wk,
                                                  const float* __restrict__ wv,
                                                  const float* __restrict__ wp,
                                                  const float* __restrict__ x,
                                                  __bf16* __restrict__ wqt,
                                                  __bf16* __restrict__ wkt,
                                                  __bf16* __restrict__ wvt,
                                                  __bf16* __restrict__ wpt,
                                                  float* __restrict__ gpart) {
    int t = threadIdx.x;
    if (blockIdx.x < 4) {   // weight transpose + bf16 convert
        int m = blockIdx.x;
        const float* src = (m == 0) ? wq : (m == 1) ? wk : (m == 2) ? wv : wp;
        __bf16* dst      = (m == 0) ? wqt : (m == 1) ? wkt : (m == 2) ? wvt : wpt;
        __shared__ float s[64][65];
        for (int i = 0; i < 16; ++i) {
            int e = i * 256 + t;
            s[e >> 6][e & 63] = src[e];
        }
        __syncthreads();
        int o = t >> 2, seg = t & 3;
        for (int j = 0; j < 16; ++j) {
            int in = seg * 16 + j;
            dst[o * 64 + in] = (__bf16)s[in][o];
        }
        return;
    }
    // GN partial sums: 512 blocks = 8b x 64 slabs of 64 rows
    int bid = blockIdx.x - 4;
    int b = bid >> 6, slab = bid & 63;
    const float4* xb = (const float4*)(x + (size_t)(b * NTOK + slab * 64) * CH);
    float s = 0.f, ss = 0.f;
    for (int i = 0; i < 4; ++i) {
        int row = (t >> 4) + i * 16;
        float4 v = xb[row * 16 + (t & 15)];
        s  += v.x + v.y + v.z + v.w;
        ss += v.x * v.x + v.y * v.y + v.z * v.z + v.w * v.w;
    }
    __shared__ float ls[256], lss[256];
    ls[t] = s; lss[t] = ss;
    __syncthreads();
    if (t < 8) {
        float a = 0.f, aa = 0.f;
        for (int p = 0; p < 16; ++p) {
            a  += ls[p * 16 + 2 * t]  + ls[p * 16 + 2 * t + 1];
            aa += lss[p * 16 + 2 * t] + lss[p * 16 + 2 * t + 1];
        }
        gpart[((b * 64 + slab) * 8 + t) * 2 + 0] = a;
        gpart[((b * 64 + slab) * 8 + t) * 2 + 1] = aa;
    }
}

// ---------------- fused GN + QKV projection (grid 512, 64 rows/block) --------------------
// Latency-chain rev: x fragments loaded (coalesced float4 x4/lane) at kernel entry, hidden
// under W staging + gpart gather; GN applied IN-REGISTER (fragment channel blocks = groups
// quad and 4+quad) -> no Hl LDS round-trip; Q packed like K (attn aq layout == kp layout)
// via Qst LDS -> one 16B store/lane instead of 16 scalar global byte-stores. 3 barriers.
// Outputs (all fp8 e4m3):
//  qp : [b][tile16 (256)][lane64][16B]  bytes0-7 = Q[tile*16+l15][quad*8..], 8-15 = +32
//  kp : same layout for K (both scaled by QK_SCALE)
//  vp : [b][kt32 (128)][chunk2][lane64][16B] chunk c: bytes0-7 = td=2c A-frag, 8-15 = td=2c+1
__global__ __launch_bounds__(256) void qkv_gn(const float* __restrict__ x,
                                              const float* __restrict__ gpart,
                                              const float* __restrict__ gamma,
                                              const float* __restrict__ beta,
                                              const __bf16* __restrict__ wqt,
                                              const __bf16* __restrict__ wkt,
                                              const __bf16* __restrict__ wvt,
                                              const float* __restrict__ bq,
                                              const float* __restrict__ bk,
                                              const float* __restrict__ bv,
                                              unsigned char* __restrict__ qp,
                                              unsigned char* __restrict__ kp,
                                              unsigned char* __restrict__ vp) {
    __shared__ __bf16 W[3][64][72];
    __shared__ _Float16 Vst[64][68];
    __shared__ unsigned char Qst[64][72];
    __shared__ unsigned char Kst[64][72];
    __shared__ float red[128];
    __shared__ float sstat[16];
    __shared__ float sg[64], sb2[64];
    int t = threadIdx.x;
    size_t rowbase = (size_t)blockIdx.x * 64;
    int b = (int)(rowbase >> 12), tokbase = (int)(rowbase & 4095);
    int lane = t & 63, wave = t >> 6, quad = lane >> 4, l15 = lane & 15;
    int row = wave * 16 + l15;

    // hoisted coalesced x fragment loads (row stride 256B; 4 lanes x 32B per row half)
    const float* xr = x + (rowbase + row) * 64;
    float4 xl0 = *(const float4*)(xr + quad * 8);
    float4 xl1 = *(const float4*)(xr + quad * 8 + 4);
    float4 xh0 = *(const float4*)(xr + 32 + quad * 8);
    float4 xh1 = *(const float4*)(xr + 32 + quad * 8 + 4);

    for (int m = 0; m < 3; ++m) {
        const __bf16* src = (m == 0) ? wqt : (m == 1) ? wkt : wvt;
        for (int i = 0; i < 2; ++i) {
            int e = i * 256 + t, rr = e >> 3, ch = e & 7;
            *(bf8*)&W[m][rr][ch * 8] = *(const bf8*)(src + rr * 64 + ch * 8);
        }
    }
    if (t < 64) { sg[t] = gamma[t]; sb2[t] = beta[t]; }
    if (t < 64) {
        int gi = t & 7, c = t >> 3;
        const float2* gp = (const float2*)gpart + (size_t)b * 512 + gi;
        float a = 0.f, aa = 0.f;
        for (int p = c * 8; p < c * 8 + 8; ++p) {
            float2 v = gp[(size_t)p * 8];
            a += v.x; aa += v.y;
        }
        red[t * 2] = a; red[t * 2 + 1] = aa;
    }
    __syncthreads();
    if (t < 8) {
        float a = 0.f, aa = 0.f;
        for (int c = 0; c < 8; ++c) {
            a  += red[(c * 8 + t) * 2];
            aa += red[(c * 8 + t) * 2 + 1];
        }
        float mean = a * (1.f / 32768.f);
        float var = aa * (1.f / 32768.f) - mean * mean;
        sstat[t * 2 + 0] = mean;
        sstat[t * 2 + 1] = rsqrtf(var + 1e-3f);
    }
    __syncthreads();

    // in-register GN -> bf16 A-fragments (channels quad*8.. = group quad; +32 = group 4+quad)
    bf8 a0, a1;
    {
        float mlo = sstat[quad * 2], rlo = sstat[quad * 2 + 1];
        float mhi = sstat[(4 + quad) * 2], rhi = sstat[(4 + quad) * 2 + 1];
        float xl[8] = {xl0.x, xl0.y, xl0.z, xl0.w, xl1.x, xl1.y, xl1.z, xl1.w};
        float xh[8] = {xh0.x, xh0.y, xh0.z, xh0.w, xh1.x, xh1.y, xh1.z, xh1.w};
#pragma unroll
        for (int j = 0; j < 8; ++j) {
            int c = quad * 8 + j;
            a0[j] = (__bf16)((xl[j] - mlo) * sg[c] * rlo + sb2[c]);
            a1[j] = (__bf16)((xh[j] - mhi) * sg[32 + c] * rhi + sb2[32 + c]);
        }
    }

    for (int m = 0; m < 3; ++m) {
        const float* bias = (m == 0) ? bq : (m == 1) ? bk : bv;
        float sc = (m == 2) ? 1.0f : QK_SCALE;
        for (int tt = 0; tt < 4; ++tt) {
            int col = l15 + 16 * tt;
            bf8 b0 = *(const bf8*)&W[m][col][quad * 8];
            bf8 b1 = *(const bf8*)&W[m][col][32 + quad * 8];
            f4 acc = {0.f, 0.f, 0.f, 0.f};
            acc = mfma16(a0, b0, acc);
            acc = mfma16(a1, b1, acc);
            float bb = bias[col];
            if (m == 2) {
                for (int r = 0; r < 4; ++r)
                    Vst[col][wave * 16 + quad * 4 + r] = (_Float16)(acc[r] + bb);
            } else if (m == 1) {
                for (int r = 0; r < 4; ++r)
                    Kst[wave * 16 + quad * 4 + r][col] = to_fp8((acc[r] + bb) * sc);
            } else {
                for (int r = 0; r < 4; ++r)
                    Qst[wave * 16 + quad * 4 + r][col] = to_fp8((acc[r] + bb) * sc);
            }
        }
    }
    __syncthreads();
    {   // packed fp8 K + Q writeout: wave = key16-tile index within block
        const unsigned char* krow = &Kst[wave * 16 + l15][0];
        lx2 kk; kk[0] = *(const long*)(krow + quad * 8);
        kk[1] = *(const long*)(krow + 32 + quad * 8);
        *(lx2*)(kp + (((size_t)b * 256 + (tokbase >> 4) + wave) * 64 + lane) * 16) = kk;
        const unsigned char* qrow = &Qst[wave * 16 + l15][0];
        lx2 qq; qq[0] = *(const long*)(qrow + quad * 8);
        qq[1] = *(const long*)(qrow + 32 + quad * 8);
        *(lx2*)(qp + (((size_t)b * 256 + (tokbase >> 4) + wave) * 64 + lane) * 16) = qq;
    }
    {   // packed fp8 V writeout (wave = td): two 32-key tiles per block
        int d = wave * 16 + l15;
        for (int kb = 0; kb < 2; ++kb) {
            h4 lo = *(const h4*)&Vst[d][kb * 32 + quad * 4];
            h4 hi = *(const h4*)&Vst[d][kb * 32 + 16 + quad * 4];
            int d0 = __builtin_amdgcn_cvt_pk_fp8_f32((float)lo[0], (float)lo[1], 0, false);
            d0     = __builtin_amdgcn_cvt_pk_fp8_f32((float)lo[2], (float)lo[3], d0, true);
            int d1 = __builtin_amdgcn_cvt_pk_fp8_f32((float)hi[0], (float)hi[1], 0, false);
            d1     = __builtin_amdgcn_cvt_pk_fp8_f32((float)hi[2], (float)hi[3], d1, true);
            long v8 = (long)(unsigned int)d0 | ((long)d1 << 32);
            int kt = (tokbase >> 5) + kb;
            *(long*)(vp + ((((size_t)b * 128 + kt) * 2 + (wave >> 1)) * 64 + lane) * 16
                        + (wave & 1) * 8) = v8;
        }
    }
}

// ---------------- fused attention + output projection + residual -------------------------
// grid 512 = qt*8 + b; block 256 = 4 waves; wave owns 1024 keys = 32 iters x 32 keys.
// fp8: per 32-key iter 4 x 16B/lane contiguous loads (2 packed K tiles + 2 packed V chunks).
// Q prologue now 4 x 16B packed loads (qp layout == kp layout).
__device__ __forceinline__ void load_kv(const unsigned char* kpw, const unsigned char* vpw,
                                        long kf[4], long vf[4]) {
    lx2 a = *(const lx2*)(kpw);
    lx2 b = *(const lx2*)(kpw + 1024);
    lx2 c = *(const lx2*)(vpw);
    lx2 d = *(const lx2*)(vpw + 1024);
    kf[0] = a[0]; kf[1] = a[1]; kf[2] = b[0]; kf[3] = b[1];
    vf[0] = c[0]; vf[1] = c[1]; vf[2] = d[0]; vf[3] = d[1];
}

__device__ __forceinline__ void compute32(const long kf[4], const long vf[4],
                                          const long aqlo[4], const long aqhi[4],
                                          long ones, f4 acc[4][4], f4 acc_li[4]) {
#pragma unroll
    for (int s = 0; s < 4; ++s) {
        f4 St0 = {0.f, 0.f, 0.f, 0.f};
        f4 St1 = {0.f, 0.f, 0.f, 0.f};
        St0 = mfma8(kf[0], aqlo[s], St0);
        St0 = mfma8(kf[1], aqhi[s], St0);
        St1 = mfma8(kf[2], aqlo[s], St1);
        St1 = mfma8(kf[3], aqhi[s], St1);
        float p00 = __builtin_amdgcn_exp2f(St0[0]);
        float p01 = __builtin_amdgcn_exp2f(St0[1]);
        float p02 = __builtin_amdgcn_exp2f(St0[2]);
        float p03 = __builtin_amdgcn_exp2f(St0[3]);
        float p10 = __builtin_amdgcn_exp2f(St1[0]);
        float p11 = __builtin_amdgcn_exp2f(St1[1]);
        float p12 = __builtin_amdgcn_exp2f(St1[2]);
        float p13 = __builtin_amdgcn_exp2f(St1[3]);
        int d0 = __builtin_amdgcn_cvt_pk_fp8_f32(p00, p01, 0, false);
        d0     = __builtin_amdgcn_cvt_pk_fp8_f32(p02, p03, d0, true);
        int d1 = __builtin_amdgcn_cvt_pk_fp8_f32(p10, p11, 0, false);
        d1     = __builtin_amdgcn_cvt_pk_fp8_f32(p12, p13, d1, true);
        long pf = (long)(unsigned int)d0 | ((long)d1 << 32);
        acc_li[s] = mfma8(ones, pf, acc_li[s]);             // row-sum of p (denominator)
        acc[s][0] = mfma8(vf[0], pf, acc[s][0]);
        acc[s][1] = mfma8(vf[1], pf, acc[s][1]);
        acc[s][2] = mfma8(vf[2], pf, acc[s][2]);
        acc[s][3] = mfma8(vf[3], pf, acc[s][3]);
    }
}

__global__ __launch_bounds__(256, 2) void attn_final(const unsigned char* __restrict__ qp,
                                                     const unsigned char* __restrict__ kp,
                                                     const unsigned char* __restrict__ vp,
                                                     const __bf16* __restrict__ wpt,
                                                     const float* __restrict__ bp,
                                                     const float* __restrict__ x,
                                                     const float* __restrict__ gpart,
                                                     const float* __restrict__ gamma,
                                                     const float* __restrict__ beta,
                                                     float* __restrict__ out) {
    __shared__ _Float16 Om[2][64][72];
    __shared__ float sS[2][64];
    __shared__ __bf16 Wl[64][72];
    __shared__ __bf16 Ol[64][72];
    __shared__ float red[128];
    __shared__ float sstat[16], sg[64], sb[64];

    int bid = blockIdx.x;
    int qt = bid >> 3, b = bid & 7;
    int t = threadIdx.x, lane = t & 63, w = t >> 6, quad = lane >> 4, l15 = lane & 15;

    for (int i = 0; i < 2; ++i) {
        int e = i * 256 + t, row = e >> 3, ch = e & 7;
        *(bf8*)&Wl[row][ch * 8] = *(const bf8*)(wpt + row * 64 + ch * 8);
    }
    if (t < 64) { sg[t] = gamma[t]; sb[t] = beta[t]; }
    if (t < 64) {
        int gi = t & 7, c = t >> 3;
        const float2* gp = (const float2*)gpart + (size_t)b * 512 + gi;
        float a = 0.f, aa = 0.f;
        for (int p = c * 8; p < c * 8 + 8; ++p) {
            float2 v = gp[(size_t)p * 8];
            a += v.x; aa += v.y;
        }
        red[t * 2] = a; red[t * 2 + 1] = aa;
    }

    const unsigned char* qpb = qp + (((size_t)b * 256 + qt * 4) * 64 + lane) * 16;
    long aqlo[4], aqhi[4];
    for (int s = 0; s < 4; ++s) {
        lx2 qq = *(const lx2*)(qpb + (size_t)s * 1024);
        aqlo[s] = qq[0]; aqhi[s] = qq[1];
    }
    const unsigned char* kpw = kp + ((size_t)b * 256 + w * 64) * 1024 + lane * 16;
    const unsigned char* vpw = vp + ((size_t)b * 128 + w * 32) * 2048 + lane * 16;

    const long ones = 0x3838383838383838L;   // 8 x e4m3(1.0)

    f4 acc[4][4] = {};
    f4 acc_li[4] = {};

    // 2-deep ping-pong software pipeline over 32 key-tiles (4 loads/iter)
    long kfA[4], kfB[4], vfA[4], vfB[4];
    load_kv(kpw, vpw, kfA, vfA);
    for (int it = 0; it < 32; it += 2) {
        load_kv(kpw + (size_t)(it + 1) * 2048, vpw + (size_t)(it + 1) * 2048, kfB, vfB);
        __builtin_amdgcn_s_setprio(1);
        compute32(kfA, vfA, aqlo, aqhi, ones, acc, acc_li);
        __builtin_amdgcn_s_setprio(0);
        if (it + 2 < 32)
            load_kv(kpw + (size_t)(it + 2) * 2048, vpw + (size_t)(it + 2) * 2048, kfA, vfA);
        __builtin_amdgcn_s_setprio(1);
        compute32(kfB, vfB, aqlo, aqhi, ones, acc, acc_li);
        __builtin_amdgcn_s_setprio(0);
    }

    // denominator per query (identical in all lanes of the quad-group already)
    float li[4];
#pragma unroll
    for (int s = 0; s < 4; ++s) li[s] = acc_li[s][0];

    // 3-phase pairwise merge (18.9 KB of merge LDS)
    if (w >= 2) {   // phase 1: waves 2,3 deposit
        for (int s = 0; s < 4; ++s) {
            for (int td = 0; td < 4; ++td) {
                h4 o4;
                for (int r = 0; r < 4; ++r) o4[r] = (_Float16)acc[s][td][r];
                *(h4*)&Om[w - 2][s * 16 + l15][td * 16 + quad * 4] = o4;
            }
            if (quad == 0) sS[w - 2][s * 16 + l15] = li[s];
        }
    }
    __syncthreads();
    if (t < 8) {    // GN stats finalize (red visible now)
        float a = 0.f, aa = 0.f;
        for (int c = 0; c < 8; ++c) {
            a  += red[(c * 8 + t) * 2];
            aa += red[(c * 8 + t) * 2 + 1];
        }
        float mean = a * (1.f / 32768.f);
        float var = aa * (1.f / 32768.f) - mean * mean;
        sstat[t * 2 + 0] = mean;
        sstat[t * 2 + 1] = rsqrtf(var + 1e-3f);
    }
    if (w < 2) {    // waves 0,1 absorb
        for (int s = 0; s < 4; ++s) {
            for (int td = 0; td < 4; ++td) {
                h4 o4 = *(const h4*)&Om[w][s * 16 + l15][td * 16 + quad * 4];
                for (int r = 0; r < 4; ++r) acc[s][td][r] += (float)o4[r];
            }
            li[s] += sS[w][s * 16 + l15];
        }
    }
    __syncthreads();
    if (w < 2) {    // phase 2: deposit pair-sums
        for (int s = 0; s < 4; ++s) {
            for (int td = 0; td < 4; ++td) {
                h4 o4;
                for (int r = 0; r < 4; ++r) o4[r] = (_Float16)acc[s][td][r];
                *(h4*)&Om[w][s * 16 + l15][td * 16 + quad * 4] = o4;
            }
            if (quad == 0) sS[w][s * 16 + l15] = li[s];
        }
    }
    __syncthreads();
    {   // phase 3: combine + normalize into Ol (bf16)
        int qq = t >> 2, ds = (t & 3) * 16;
        float inv = 1.f / (sS[0][qq] + sS[1][qq]);
        h8 a0 = *(const h8*)&Om[0][qq][ds];
        h8 b0 = *(const h8*)&Om[0][qq][ds + 8];
        h8 a1 = *(const h8*)&Om[1][qq][ds];
        h8 b1 = *(const h8*)&Om[1][qq][ds + 8];
        bf8 olo, ohi;
        for (int j = 0; j < 8; ++j) {
            olo[j] = (__bf16)(((float)a0[j] + (float)a1[j]) * inv);
            ohi[j] = (__bf16)(((float)b0[j] + (float)b1[j]) * inv);
        }
        *(bf8*)&Ol[qq][ds] = olo;
        *(bf8*)&Ol[qq][ds + 8] = ohi;
    }
    __syncthreads();
    // epilogue: out = Ol @ wp^T + bp + GN(x)
    size_t rowbase = ((size_t)b * NTOK + qt * 64) + w * 16;
    bf8 a0 = *(const bf8*)&Ol[w * 16 + l15][quad * 8];
    bf8 a1 = *(const bf8*)&Ol[w * 16 + l15][32 + quad * 8];
    for (int tt = 0; tt < 4; ++tt) {
        int col = l15 + 16 * tt;
        bf8 b0 = *(const bf8*)&Wl[col][quad * 8];
        bf8 b1 = *(const bf8*)&Wl[col][32 + quad * 8];
        f4 pacc = {0.f, 0.f, 0.f, 0.f};
        pacc = mfma16(a0, b0, pacc);
        pacc = mfma16(a1, b1, pacc);
        int grp = col >> 3;
        float mean = sstat[grp * 2], gs = sg[col] * sstat[grp * 2 + 1], bs = sb[col];
        float bias = bp[col];
        for (int r = 0; r < 4; ++r) {
            size_t gi = (rowbase + quad * 4 + r) * 64 + col;
            float h = (x[gi] - mean) * gs + bs;
            out[gi] = pacc[r] + bias + h;
        }
    }
}

extern "C" void kernel_launch(void* const* d_in, const int* in_sizes, int n_in,
                              void* d_out, int out_size, void* d_ws, size_t ws_size,
                              hipStream_t stream) {
    const float* x     = (const float*)d_in[0];
    const float* gamma = (const float*)d_in[1];
    const float* beta  = (const float*)d_in[2];
    const float* wq    = (const float*)d_in[3];
    const float* bq    = (const float*)d_in[4];
    const float* wk    = (const float*)d_in[5];
    const float* bk    = (const float*)d_in[6];
    const float* wv    = (const float*)d_in[7];
    const float* bv    = (const float*)d_in[8];
    const float* wp    = (const float*)d_in[9];
    const float* bp    = (const float*)d_in[10];
    float* out = (float*)d_out;

    char* ws = (char*)d_ws;
    const size_t MB = 1024 * 1024;
    unsigned char* qpb = (unsigned char*)(ws);            // 2 MB fp8 Q packed tiles
    unsigned char* kpb = (unsigned char*)(ws + 2 * MB);   // 2 MB fp8 K packed tiles
    unsigned char* vpb = (unsigned char*)(ws + 4 * MB);   // 2 MB fp8 V packed chunks
    __bf16*   wqt  = (__bf16*)(ws + 12 * MB);
    __bf16*   wkt  = (__bf16*)(ws + 12 * MB + 8192);
    __bf16*   wvt  = (__bf16*)(ws + 12 * MB + 16384);
    __bf16*   wpt  = (__bf16*)(ws + 12 * MB + 24576);
    float*    gpart = (float*)(ws + 12 * MB + 32768);     // 32 KB

    pre_kernel<<<516, 256, 0, stream>>>(wq, wk, wv, wp, x, wqt, wkt, wvt, wpt, gpart);
    qkv_gn<<<512, 256, 0, stream>>>(x, gpart, gamma, beta, wqt, wkt, wvt, bq, bk, bv,
                                    qpb, kpb, vpb);
    attn_final<<<512, 256, 0, stream>>>(qpb, kpb, vpb, wpt, bp, x, gpart, gamma, beta, out);
}